// Round 4
// baseline (252.249 us; speedup 1.0000x reference)
//
#include <hip/hip_runtime.h>
#include <math.h>

#define N_TOK 4098
#define NK_TOK 4099
#define C_DIM 384
#define NKPAD 4160
// HEADS = 6, HD = 64

typedef short  bh8 __attribute__((ext_vector_type(8)));   // 8 bf16 (4 VGPRs)
typedef float  f32x4 __attribute__((ext_vector_type(4)));
typedef unsigned short ushort;
typedef ushort u4 __attribute__((ext_vector_type(4)));
typedef ushort u8 __attribute__((ext_vector_type(8)));

static __device__ __forceinline__ ushort f2bf(float f) {
  unsigned int u = __float_as_uint(f);
  u = (u + 0x7FFF + ((u >> 16) & 1)) >> 16;   // RNE
  return (ushort)u;
}
static __device__ __forceinline__ float bf2f(ushort s) {
  return __uint_as_float(((unsigned int)s) << 16);
}

typedef const __attribute__((address_space(1))) unsigned int* gas_t;
typedef __attribute__((address_space(3))) unsigned int* las_t;
static __device__ __forceinline__ void gload16(const void* g, void* l) {
  // async global->LDS, 16B per lane; dest = wave-uniform base + lane*16
  __builtin_amdgcn_global_load_lds((gas_t)g, (las_t)l, 16, 0, 0);
}

// Stage a 64x64 bf16 tile (global row stride rs ushorts) into LDS with an
// XOR-8 swizzle: stored chunk (r, c8) holds source cols (c8^(r&7))*8..+7.
static __device__ __forceinline__ void stage_tile(const ushort* src, int rs,
                                                  ushort* lds, int t) {
#pragma unroll
  for (int it = 0; it < 2; ++it) {
    const int base = it * 256 + (t & 192);     // wave-uniform
    const int i = base + (t & 63);
    const int r = i >> 3, c8 = i & 7;
    gload16(src + r * rs + ((c8 ^ (r & 7)) << 3), lds + base * 8);
  }
}
static __device__ __forceinline__ bh8 frag(const ushort* lds, int row, int c8) {
  return *(const bh8*)&lds[(row << 6) + ((c8 ^ (row & 7)) << 3)];
}

// ---------------------------------------------------------------------------
// pool partials (no atomics, no memset needed); block 128 zeroes done[]
__global__ __launch_bounds__(384) void pool_kernel(
    const float* __restrict__ x, const float* __restrict__ mask,
    float* __restrict__ pooled_part, float* __restrict__ cnt_part,
    int* __restrict__ done) {
  const int b = blockIdx.x, t = threadIdx.x;
  if (b == 128) { if (t < 198) done[t] = 0; return; }
  const int r0 = b * 32;
  float acc = 0.f;
  int lc = 0;
  for (int r = r0; r < r0 + 32; ++r)
    if (mask[r] < 0.5f) { acc += x[(size_t)(r + 1) * C_DIM + t]; ++lc; }
  pooled_part[b * C_DIM + t] = acc;
  if (t == 0) cnt_part[b] = (float)lc;
}

// ---------------------------------------------------------------------------
// prep: blocks 0..259 build bf16 A-matrices (16 rows each); block 256 first
// reduces pool partials -> back token (row 4098). blocks 260..291 convert W.
// block 292: single-block keep-compaction prefix scan -> inv[], nk.
__global__ __launch_bounds__(256) void prep_kernel(
    const float* __restrict__ x, const float* __restrict__ pos,
    const float* __restrict__ pooled_part, const float* __restrict__ cnt_part,
    const float* __restrict__ Wq, const float* __restrict__ Wk,
    const float* __restrict__ Wv, const float* __restrict__ Wp,
    const float* __restrict__ mask, const float* __restrict__ mask_block,
    ushort* __restrict__ Aq, ushort* __restrict__ Ak, ushort* __restrict__ Av,
    ushort* __restrict__ Wb, int* __restrict__ nk, int* __restrict__ inv) {
  const int b = blockIdx.x, t = threadIdx.x;
  if (b < 260) {
    __shared__ float sback[C_DIM];
    if (b == 256) {                         // back token for row 4098
      float cs = 0.f;
      for (int i = (t & 63); i < 128; i += 64) cs += cnt_part[i];
#pragma unroll
      for (int d = 1; d < 64; d <<= 1) cs += __shfl_xor(cs, d);
      const float ic = 1.f / (cs + 1e-10f);
      for (int c = t; c < C_DIM; c += 256) {
        float s = 0.f;
        for (int p = 0; p < 128; ++p) s += pooled_part[p * C_DIM + c];
        sback[c] = s * ic;
      }
      __syncthreads();
    }
    const int r0 = b * 16;
#pragma unroll
    for (int i = 0; i < 6; ++i) {
      const int idx = i * 1024 + t * 4;
      const int row = r0 + idx / C_DIM, col = idx % C_DIM;
      if (row >= NK_TOK) continue;
      const float4 pv = *(const float4*)&pos[(size_t)row * C_DIM + col];
      float4 xv;
      if (row == NK_TOK - 1)
        xv = make_float4(sback[col], sback[col + 1], sback[col + 2], sback[col + 3]);
      else
        xv = *(const float4*)&x[(size_t)row * C_DIM + col];
      if (row < N_TOK) {
        u4 q4 = {f2bf((xv.x + pv.x) * 0.125f), f2bf((xv.y + pv.y) * 0.125f),
                 f2bf((xv.z + pv.z) * 0.125f), f2bf((xv.w + pv.w) * 0.125f)};
        *(u4*)&Aq[(size_t)row * C_DIM + col] = q4;
      }
      u4 k4 = {f2bf(xv.x + pv.x), f2bf(xv.y + pv.y),
               f2bf(xv.z + pv.z), f2bf(xv.w + pv.w)};
      *(u4*)&Ak[(size_t)row * C_DIM + col] = k4;
      u4 v4 = {f2bf(xv.x), f2bf(xv.y), f2bf(xv.z), f2bf(xv.w)};
      *(u4*)&Av[(size_t)row * C_DIM + col] = v4;
    }
  } else if (b < 292) {
    const int wi = b - 260;                  // 0..31; 8 blocks per weight
    const float* src = (wi < 8) ? Wq : (wi < 16) ? Wk : (wi < 24) ? Wv : Wp;
    const int base = (wi >> 3) * 147456 + (wi & 7) * 18432;
#pragma unroll 2
    for (int i = 0; i < 18; ++i) {
      const int g = base + i * 1024 + t * 4;
      const float4 v = *(const float4*)&src[g - (wi >> 3) * 147456 + 0];
      // note: src offset is within one 147456 matrix
      u4 o = {f2bf(v.x), f2bf(v.y), f2bf(v.z), f2bf(v.w)};
      *(u4*)&Wb[g] = o;
    }
  } else {
    // keep-compaction: 256 threads x 17 elements, block prefix scan
    __shared__ int scnt[256];
    const int j0 = t * 17;
    unsigned int bits = 0;
    int c = 0;
#pragma unroll 1
    for (int u = 0; u < 17; ++u) {
      const int j = j0 + u;
      bool keep = false;
      if (j < NK_TOK)
        keep = (j >= 1 && j <= N_TOK - 2) ? (mask[j - 1] >= 0.5f)
                                          : (mask_block[j] >= 0.5f);
      if (keep) { bits |= 1u << u; ++c; }
    }
    scnt[t] = c;
    __syncthreads();
    for (int d = 1; d < 256; d <<= 1) {
      const int v = scnt[t];
      const int add = (t >= d) ? scnt[t - d] : 0;
      __syncthreads();
      scnt[t] = v + add;
      __syncthreads();
    }
    int base = scnt[t] - c;                  // exclusive prefix
    if (t == 255) *nk = scnt[255];
#pragma unroll 1
    for (int u = 0; u < 17; ++u) {
      const int j = j0 + u;
      if (j < NK_TOK) inv[j] = ((bits >> u) & 1) ? base++ : -1;
    }
  }
}

// ---------------------------------------------------------------------------
// bf16 MFMA GEMM core: 64x64 out tile, K=384, BK=64, double-buffered
// global_load_lds staging.
static __device__ __forceinline__ void gemm_core(const ushort* A, const ushort* B,
    ushort* As, ushort* Bs, int t, int w, int quad, int l15, f32x4 acc[4]) {
  stage_tile(A, C_DIM, As, t);
  stage_tile(B, C_DIM, Bs, t);
  __syncthreads();
#pragma unroll
  for (int kt = 0; kt < 6; ++kt) {
    const int cur = (kt & 1) << 12;
    if (kt < 5) {
      stage_tile(A + (kt + 1) * 64, C_DIM, As + (cur ^ 4096), t);
      stage_tile(B + (kt + 1) * 64, C_DIM, Bs + (cur ^ 4096), t);
    }
    const bh8 b0 = frag(Bs + cur, w * 16 + l15, quad);
    const bh8 b1 = frag(Bs + cur, w * 16 + l15, 4 + quad);
#pragma unroll
    for (int mb = 0; mb < 4; ++mb) {
      const bh8 a0 = frag(As + cur, mb * 16 + l15, quad);
      const bh8 a1 = frag(As + cur, mb * 16 + l15, 4 + quad);
      acc[mb] = __builtin_amdgcn_mfma_f32_16x16x32_bf16(a0, b0, acc[mb], 0, 0, 0);
      acc[mb] = __builtin_amdgcn_mfma_f32_16x16x32_bf16(a1, b1, acc[mb], 0, 0, 0);
    }
    __syncthreads();
  }
}

// fused Q/K/V projection. y = which*6 + h. K epilogue scatters compacted rows
// via inv[]; V epilogue scatters compacted AND transposed (Vt[h][d][slot]).
__global__ __launch_bounds__(256) void gemm3_kernel(
    const ushort* __restrict__ Aq, const ushort* __restrict__ Ak,
    const ushort* __restrict__ Av, const ushort* __restrict__ Wb,
    const int* __restrict__ inv, ushort* __restrict__ Qh,
    ushort* __restrict__ Kc, ushort* __restrict__ Vt) {
  __shared__ ushort As[8192], Bs[8192];
  const int t = threadIdx.x, w = t >> 6, lane = t & 63;
  const int quad = lane >> 4, l15 = lane & 15;
  const int m0 = blockIdx.x * 64;
  const int which = blockIdx.y / 6, h = blockIdx.y % 6;
  const ushort* A = (which == 0 ? Aq : which == 1 ? Ak : Av) + (size_t)m0 * C_DIM;
  const ushort* B = Wb + (size_t)which * 147456 + (size_t)h * 64 * C_DIM;
  f32x4 acc[4];
#pragma unroll
  for (int i = 0; i < 4; ++i) acc[i] = (f32x4){0.f, 0.f, 0.f, 0.f};
  gemm_core(A, B, As, Bs, t, w, quad, l15, acc);
  const int n = w * 16 + l15;
  if (which == 0) {
#pragma unroll
    for (int mb = 0; mb < 4; ++mb)
#pragma unroll
      for (int r = 0; r < 4; ++r) {
        const int m = m0 + mb * 16 + quad * 4 + r;
        if (m < N_TOK) Qh[((size_t)h * N_TOK + m) * 64 + n] = f2bf(acc[mb][r]);
      }
  } else if (which == 1) {
#pragma unroll
    for (int mb = 0; mb < 4; ++mb)
#pragma unroll
      for (int r = 0; r < 4; ++r) {
        const int m = m0 + mb * 16 + quad * 4 + r;
        if (m < NK_TOK) {
          const int slot = inv[m];
          if (slot >= 0) Kc[((size_t)h * NKPAD + slot) * 64 + n] = f2bf(acc[mb][r]);
        }
      }
  } else {
#pragma unroll
    for (int mb = 0; mb < 4; ++mb)
#pragma unroll
      for (int r = 0; r < 4; ++r) {
        const int m = m0 + mb * 16 + quad * 4 + r;
        if (m < NK_TOK) {
          const int slot = inv[m];
          if (slot >= 0) Vt[((size_t)h * 64 + n) * NKPAD + slot] = f2bf(acc[mb][r]);
        }
      }
  }
}

// output projection: fp32 out + bias
__global__ __launch_bounds__(256) void gemm_out_kernel(
    const ushort* __restrict__ Am, const ushort* __restrict__ Wpb,
    const float* __restrict__ bp, float* __restrict__ out) {
  __shared__ ushort As[8192], Bs[8192];
  const int t = threadIdx.x, w = t >> 6, lane = t & 63;
  const int quad = lane >> 4, l15 = lane & 15;
  const int m0 = blockIdx.x * 64;
  const int h = blockIdx.y;
  f32x4 acc[4];
#pragma unroll
  for (int i = 0; i < 4; ++i) acc[i] = (f32x4){0.f, 0.f, 0.f, 0.f};
  gemm_core(Am + (size_t)m0 * C_DIM, Wpb + (size_t)h * 64 * C_DIM,
            As, Bs, t, w, quad, l15, acc);
  const int n = w * 16 + l15;
  const float bb = bp[h * 64 + n];
#pragma unroll
  for (int mb = 0; mb < 4; ++mb)
#pragma unroll
    for (int r = 0; r < 4; ++r) {
      const int m = m0 + mb * 16 + quad * 4 + r;
      if (m < N_TOK) out[(size_t)m * C_DIM + h * 64 + n] = acc[mb][r] + bb;
    }
}

// ---------------------------------------------------------------------------
// MFMA flash attention, 32 queries/wave, double-buffered swizzled staging,
// no-max softmax. grid (33 q-tiles of 128, 6 heads, 3 key slices).
// Last slice to finish (done-counter protocol) merges the 3 partials -> Am.
__global__ __launch_bounds__(256) void attn_kernel(
    const ushort* __restrict__ Qh, const ushort* __restrict__ Kc,
    const ushort* __restrict__ Vt, const int* __restrict__ nkp,
    ushort* __restrict__ Opart, float* __restrict__ Lpart,
    int* __restrict__ done, ushort* __restrict__ Am) {
  __shared__ ushort KsB[8192], VsB[8192];
  __shared__ ushort Ps[4][32][72];
  __shared__ int sdone;
  const int t = threadIdx.x, w = t >> 6, lane = t & 63;
  const int quad = lane >> 4, l15 = lane & 15;
  const int h = blockIdx.y, slice = blockIdx.z;
  const int q0 = blockIdx.x * 128;
  const int nk = *nkp, nchunk = (nk + 63) >> 6;

  bh8 qf[2][2];
#pragma unroll
  for (int g = 0; g < 2; ++g) {
    int qr = q0 + w * 32 + g * 16 + l15;
    if (qr > N_TOK - 1) qr = N_TOK - 1;        // clamp (stores guarded)
    const ushort* qp = Qh + ((size_t)h * N_TOK + qr) * 64 + quad * 8;
    qf[g][0] = *(const bh8*)qp;
    qf[g][1] = *(const bh8*)(qp + 32);
  }
  f32x4 oacc[2][4];
#pragma unroll
  for (int g = 0; g < 2; ++g)
#pragma unroll
    for (int i = 0; i < 4; ++i) oacc[g][i] = (f32x4){0.f, 0.f, 0.f, 0.f};
  float l_r[2] = {0.f, 0.f};

  const ushort* kb = Kc + (size_t)h * NKPAD * 64;
  const ushort* vb = Vt + (size_t)h * 64 * NKPAD;

  if (slice < nchunk) {
    stage_tile(kb + (size_t)slice * 4096, 64, KsB, t);
    stage_tile(vb + slice * 64, NKPAD, VsB, t);
  }
  __syncthreads();
  int bsel = 0;
  for (int kc = slice; kc < nchunk; kc += 3) {
    if (kc + 3 < nchunk) {                     // async prefetch next chunk
      stage_tile(kb + (size_t)(kc + 3) * 4096, 64, KsB + ((bsel ^ 1) << 12), t);
      stage_tile(vb + (kc + 3) * 64, NKPAD, VsB + ((bsel ^ 1) << 12), t);
    }
    const ushort* ks = KsB + (bsel << 12);
    const ushort* vs = VsB + (bsel << 12);
#pragma unroll
    for (int g = 0; g < 2; ++g) {
      float csum = 0.f;
#pragma unroll
      for (int f = 0; f < 4; ++f) {
        f32x4 s4 = {0.f, 0.f, 0.f, 0.f};
        const bh8 a0 = frag(ks, f * 16 + l15, quad);
        const bh8 a1 = frag(ks, f * 16 + l15, 4 + quad);
        s4 = __builtin_amdgcn_mfma_f32_16x16x32_bf16(a0, qf[g][0], s4, 0, 0, 0);
        s4 = __builtin_amdgcn_mfma_f32_16x16x32_bf16(a1, qf[g][1], s4, 0, 0, 0);
        const int keyb = kc * 64 + f * 16 + quad * 4;
        u4 pv;
#pragma unroll
        for (int r = 0; r < 4; ++r) {
          const float p = (keyb + r < nk) ? __expf(s4[r]) : 0.f;
          csum += p;
          pv[r] = f2bf(p);
        }
        *(u4*)&Ps[w][g * 16 + l15][f * 16 + quad * 4] = pv;
      }
      csum += __shfl_xor(csum, 16);
      csum += __shfl_xor(csum, 32);
      l_r[g] += csum;
    }
    bh8 pa[2][2];
#pragma unroll
    for (int g = 0; g < 2; ++g) {
      pa[g][0] = *(const bh8*)&Ps[w][g * 16 + l15][quad * 8];
      pa[g][1] = *(const bh8*)&Ps[w][g * 16 + l15][32 + quad * 8];
    }
#pragma unroll
    for (int db = 0; db < 4; ++db) {
      const bh8 b0 = frag(vs, db * 16 + l15, quad);
      const bh8 b1 = frag(vs, db * 16 + l15, 4 + quad);
#pragma unroll
      for (int g = 0; g < 2; ++g) {
        oacc[g][db] = __builtin_amdgcn_mfma_f32_16x16x32_bf16(pa[g][0], b0, oacc[g][db], 0, 0, 0);
        oacc[g][db] = __builtin_amdgcn_mfma_f32_16x16x32_bf16(pa[g][1], b1, oacc[g][db], 0, 0, 0);
      }
    }
    __syncthreads();
    bsel ^= 1;
  }
  const int sh = slice * 6 + h;
#pragma unroll
  for (int g = 0; g < 2; ++g) {
#pragma unroll
    for (int db = 0; db < 4; ++db)
#pragma unroll
      for (int r = 0; r < 4; ++r) {
        const int q = q0 + w * 32 + g * 16 + quad * 4 + r;
        if (q < N_TOK)
          Opart[((size_t)sh * NKPAD + q) * 64 + db * 16 + l15] = f2bf(oacc[g][db][r]);
      }
    if (quad == 0) {
      const int q = q0 + w * 32 + g * 16 + l15;
      if (q < N_TOK) Lpart[sh * NKPAD + q] = l_r[g];
    }
  }

  // last-block merge: 3 slices of (q-tile, h) -> Am bf16
  __threadfence();
  if (t == 0) sdone = atomicAdd(&done[blockIdx.x * 6 + h], 1);
  __syncthreads();
  if (sdone != 2) return;
  __threadfence();
#pragma unroll
  for (int i = 0; i < 4; ++i) {
    const int q = q0 + i * 32 + (t >> 3);
    if (q >= N_TOK) continue;
    const int d = (t & 7) * 8;
    float l = 0.f;
#pragma unroll
    for (int s = 0; s < 3; ++s) l += Lpart[(s * 6 + h) * NKPAD + q];
    const float invl = 1.f / l;
    float o[8] = {0.f, 0.f, 0.f, 0.f, 0.f, 0.f, 0.f, 0.f};
#pragma unroll
    for (int s = 0; s < 3; ++s) {
      const u8 v = *(const u8*)&Opart[((size_t)(s * 6 + h) * NKPAD + q) * 64 + d];
#pragma unroll
      for (int j = 0; j < 8; ++j) o[j] += bf2f(v[j]);
    }
    u8 rr;
#pragma unroll
    for (int j = 0; j < 8; ++j) rr[j] = f2bf(o[j] * invl);
    *(u8*)&Am[(size_t)q * C_DIM + h * 64 + d] = rr;
  }
}

// ---------------------------------------------------------------------------
extern "C" void kernel_launch(void* const* d_in, const int* in_sizes, int n_in,
                              void* d_out, int out_size, void* d_ws, size_t ws_size,
                              hipStream_t stream) {
  const float* x          = (const float*)d_in[0];
  const float* pos        = (const float*)d_in[1];
  const float* mask       = (const float*)d_in[2];
  const float* mask_block = (const float*)d_in[3];
  const float* Wq         = (const float*)d_in[4];
  const float* Wk         = (const float*)d_in[5];
  const float* Wv         = (const float*)d_in[6];
  const float* Wp         = (const float*)d_in[7];
  const float* bp         = (const float*)d_in[8];
  float* out = (float*)d_out;
  char* wsb = (char*)d_ws;

  float*  pooled_part = (float*)wsb;                // [128][384]
  float*  cnt_part    = (float*)(wsb + 196608);     // [128]
  int*    nk          = (int*)(wsb + 197120);
  int*    done        = (int*)(wsb + 197632);       // [198]
  int*    inv         = (int*)(wsb + 198656);       // [4099]
  ushort* Aq          = (ushort*)(wsb + 215296);    // [4160][384]
  ushort* Ak          = (ushort*)(wsb + 3410176);   // [4160][384]
  ushort* Av          = (ushort*)(wsb + 6605056);   // [4160][384]
  ushort* Wb          = (ushort*)(wsb + 9799936);   // [4][384][384]
  ushort* Qh          = (ushort*)(wsb + 10979584);  // [6][4098][64]
  ushort* Kc          = (ushort*)(wsb + 14126848);  // [6][4160][64]
  ushort* Vt          = (ushort*)(wsb + 17321728);  // [6][64][4160]
  float*  Lp          = (float*)(wsb + 20516608);   // [18][4160]
  ushort* Am          = (ushort*)(wsb + 20816128);  // [4160][384]
  ushort* Op          = Aq;  // [18][4160][64] overlays Aq/Ak/Av (dead after gemm3)

  pool_kernel<<<dim3(129), dim3(384), 0, stream>>>(x, mask, pooled_part,
                                                   cnt_part, done);
  prep_kernel<<<dim3(293), dim3(256), 0, stream>>>(x, pos, pooled_part, cnt_part,
                                                   Wq, Wk, Wv, Wp, mask, mask_block,
                                                   Aq, Ak, Av, Wb, nk, inv);
  gemm3_kernel<<<dim3(65, 18), 256, 0, stream>>>(Aq, Ak, Av, Wb, inv, Qh, Kc, Vt);
  attn_kernel<<<dim3(33, 6, 3), 256, 0, stream>>>(Qh, Kc, Vt, nk, Op, Lp, done, Am);
  gemm_out_kernel<<<dim3(65, 6), 256, 0, stream>>>(Am, Wb + 3 * 147456, bp, out);
}

// Round 5
// 160.090 us; speedup vs baseline: 1.5757x; 1.5757x over previous
//
#include <hip/hip_runtime.h>
#include <math.h>

#define N_TOK 4098
#define NK_TOK 4099
#define C_DIM 384
#define NKPAD 4160
// HEADS = 6, HD = 64

typedef short  bh8 __attribute__((ext_vector_type(8)));   // 8 bf16 (4 VGPRs)
typedef float  f32x4 __attribute__((ext_vector_type(4)));
typedef unsigned short ushort;
typedef ushort u4 __attribute__((ext_vector_type(4)));
typedef ushort u8 __attribute__((ext_vector_type(8)));

static __device__ __forceinline__ ushort f2bf(float f) {
  unsigned int u = __float_as_uint(f);
  u = (u + 0x7FFF + ((u >> 16) & 1)) >> 16;   // RNE
  return (ushort)u;
}
static __device__ __forceinline__ float bf2f(ushort s) {
  return __uint_as_float(((unsigned int)s) << 16);
}

// ---------------------------------------------------------------------------
// pool partials (no atomics, no memset needed)
__global__ __launch_bounds__(384) void pool_kernel(
    const float* __restrict__ x, const float* __restrict__ mask,
    float* __restrict__ pooled_part, float* __restrict__ cnt_part) {
  const int b = blockIdx.x, t = threadIdx.x;
  const int r0 = b * 32;
  float acc = 0.f;
  int lc = 0;
  for (int r = r0; r < r0 + 32; ++r)
    if (mask[r] < 0.5f) { acc += x[(size_t)(r + 1) * C_DIM + t]; ++lc; }
  pooled_part[b * C_DIM + t] = acc;
  if (t == 0) cnt_part[b] = (float)lc;
}

// ---------------------------------------------------------------------------
// prep: blocks 0..259 build bf16 A-matrices (16 rows each); block 256 first
// reduces pool partials -> back token (row 4098). blocks 260..291 convert W.
// block 292: single-block keep-compaction prefix scan -> inv[], nk.
__global__ __launch_bounds__(256) void prep_kernel(
    const float* __restrict__ x, const float* __restrict__ pos,
    const float* __restrict__ pooled_part, const float* __restrict__ cnt_part,
    const float* __restrict__ Wq, const float* __restrict__ Wk,
    const float* __restrict__ Wv, const float* __restrict__ Wp,
    const float* __restrict__ mask, const float* __restrict__ mask_block,
    ushort* __restrict__ Aq, ushort* __restrict__ Ak, ushort* __restrict__ Av,
    ushort* __restrict__ Wb, int* __restrict__ nk, int* __restrict__ inv) {
  const int b = blockIdx.x, t = threadIdx.x;
  if (b < 260) {
    __shared__ float sback[C_DIM];
    if (b == 256) {                         // back token for row 4098
      float cs = 0.f;
      for (int i = (t & 63); i < 128; i += 64) cs += cnt_part[i];
#pragma unroll
      for (int d = 1; d < 64; d <<= 1) cs += __shfl_xor(cs, d);
      const float ic = 1.f / (cs + 1e-10f);
      for (int c = t; c < C_DIM; c += 256) {
        float s = 0.f;
        for (int p = 0; p < 128; ++p) s += pooled_part[p * C_DIM + c];
        sback[c] = s * ic;
      }
      __syncthreads();
    }
    const int r0 = b * 16;
#pragma unroll
    for (int i = 0; i < 6; ++i) {
      const int idx = i * 1024 + t * 4;
      const int row = r0 + idx / C_DIM, col = idx % C_DIM;
      if (row >= NK_TOK) continue;
      const float4 pv = *(const float4*)&pos[(size_t)row * C_DIM + col];
      float4 xv;
      if (row == NK_TOK - 1)
        xv = make_float4(sback[col], sback[col + 1], sback[col + 2], sback[col + 3]);
      else
        xv = *(const float4*)&x[(size_t)row * C_DIM + col];
      if (row < N_TOK) {
        u4 q4 = {f2bf((xv.x + pv.x) * 0.125f), f2bf((xv.y + pv.y) * 0.125f),
                 f2bf((xv.z + pv.z) * 0.125f), f2bf((xv.w + pv.w) * 0.125f)};
        *(u4*)&Aq[(size_t)row * C_DIM + col] = q4;
      }
      u4 k4 = {f2bf(xv.x + pv.x), f2bf(xv.y + pv.y),
               f2bf(xv.z + pv.z), f2bf(xv.w + pv.w)};
      *(u4*)&Ak[(size_t)row * C_DIM + col] = k4;
      u4 v4 = {f2bf(xv.x), f2bf(xv.y), f2bf(xv.z), f2bf(xv.w)};
      *(u4*)&Av[(size_t)row * C_DIM + col] = v4;
    }
  } else if (b < 292) {
    const int wi = b - 260;                  // 0..31; 8 blocks per weight
    const float* src = (wi < 8) ? Wq : (wi < 16) ? Wk : (wi < 24) ? Wv : Wp;
    const int base = (wi >> 3) * 147456 + (wi & 7) * 18432;
#pragma unroll 2
    for (int i = 0; i < 18; ++i) {
      const int g = base + i * 1024 + t * 4;
      const float4 v = *(const float4*)&src[(wi & 7) * 18432 + i * 1024 + t * 4];
      u4 o = {f2bf(v.x), f2bf(v.y), f2bf(v.z), f2bf(v.w)};
      *(u4*)&Wb[g] = o;
    }
  } else {
    // keep-compaction: 256 threads x 17 elements, block prefix scan
    __shared__ int scnt[256];
    const int j0 = t * 17;
    unsigned int bits = 0;
    int c = 0;
#pragma unroll 1
    for (int u = 0; u < 17; ++u) {
      const int j = j0 + u;
      bool keep = false;
      if (j < NK_TOK)
        keep = (j >= 1 && j <= N_TOK - 2) ? (mask[j - 1] >= 0.5f)
                                          : (mask_block[j] >= 0.5f);
      if (keep) { bits |= 1u << u; ++c; }
    }
    scnt[t] = c;
    __syncthreads();
    for (int d = 1; d < 256; d <<= 1) {
      const int v = scnt[t];
      const int add = (t >= d) ? scnt[t - d] : 0;
      __syncthreads();
      scnt[t] = v + add;
      __syncthreads();
    }
    int base = scnt[t] - c;                  // exclusive prefix
    if (t == 255) *nk = scnt[255];
#pragma unroll 1
    for (int u = 0; u < 17; ++u) {
      const int j = j0 + u;
      if (j < NK_TOK) inv[j] = ((bits >> u) & 1) ? base++ : -1;
    }
  }
}

// ---------------------------------------------------------------------------
// bf16 MFMA GEMM core: 64x64 out tile, K=384, BK=64, synchronous u8 staging
// with VGPR prefetch of the next K-chunk during compute. Padded LDS [64][72].
static __device__ __forceinline__ void gemm_core(
    const ushort* __restrict__ A, const ushort* __restrict__ B,
    ushort (* __restrict__ As)[72], ushort (* __restrict__ Bs)[72],
    int t, int w, int quad, int l15, f32x4 acc[4]) {
  const int g = t & 7;
  u8 ra[2], rb[2];
#pragma unroll
  for (int it = 0; it < 2; ++it) {
    const int r = it * 32 + (t >> 3);
    ra[it] = *(const u8*)&A[r * C_DIM + g * 8];
    rb[it] = *(const u8*)&B[r * C_DIM + g * 8];
  }
#pragma unroll 1
  for (int kt = 0; kt < 6; ++kt) {
    __syncthreads();                         // previous chunk's readers done
#pragma unroll
    for (int it = 0; it < 2; ++it) {
      const int r = it * 32 + (t >> 3);
      *(u8*)&As[r][g * 8] = ra[it];
      *(u8*)&Bs[r][g * 8] = rb[it];
    }
    __syncthreads();
    if (kt < 5) {
      const int k0 = (kt + 1) * 64;
#pragma unroll
      for (int it = 0; it < 2; ++it) {
        const int r = it * 32 + (t >> 3);
        ra[it] = *(const u8*)&A[r * C_DIM + k0 + g * 8];
        rb[it] = *(const u8*)&B[r * C_DIM + k0 + g * 8];
      }
    }
    const bh8 b0 = *(const bh8*)&Bs[w * 16 + l15][quad * 8];
    const bh8 b1 = *(const bh8*)&Bs[w * 16 + l15][32 + quad * 8];
#pragma unroll
    for (int mb = 0; mb < 4; ++mb) {
      const bh8 a0 = *(const bh8*)&As[mb * 16 + l15][quad * 8];
      const bh8 a1 = *(const bh8*)&As[mb * 16 + l15][32 + quad * 8];
      acc[mb] = __builtin_amdgcn_mfma_f32_16x16x32_bf16(a0, b0, acc[mb], 0, 0, 0);
      acc[mb] = __builtin_amdgcn_mfma_f32_16x16x32_bf16(a1, b1, acc[mb], 0, 0, 0);
    }
  }
}

// fused Q/K/V projection. y = which*6 + h. K/V epilogues scatter compacted
// rows via inv[] (row-major Kc/Vc).
__global__ __launch_bounds__(256) void gemm3_kernel(
    const ushort* __restrict__ Aq, const ushort* __restrict__ Ak,
    const ushort* __restrict__ Av, const ushort* __restrict__ Wb,
    const int* __restrict__ inv, ushort* __restrict__ Qh,
    ushort* __restrict__ Kc, ushort* __restrict__ Vc) {
  __shared__ ushort As[64][72], Bs[64][72];
  const int t = threadIdx.x, w = t >> 6, lane = t & 63;
  const int quad = lane >> 4, l15 = lane & 15;
  const int m0 = blockIdx.x * 64;
  const int which = blockIdx.y / 6, h = blockIdx.y % 6;
  const ushort* A = (which == 0 ? Aq : which == 1 ? Ak : Av) + (size_t)m0 * C_DIM;
  const ushort* B = Wb + (size_t)which * 147456 + (size_t)h * 64 * C_DIM;
  f32x4 acc[4];
#pragma unroll
  for (int i = 0; i < 4; ++i) acc[i] = (f32x4){0.f, 0.f, 0.f, 0.f};
  gemm_core(A, B, As, Bs, t, w, quad, l15, acc);
  const int n = w * 16 + l15;
  if (which == 0) {
#pragma unroll
    for (int mb = 0; mb < 4; ++mb)
#pragma unroll
      for (int r = 0; r < 4; ++r) {
        const int m = m0 + mb * 16 + quad * 4 + r;
        if (m < N_TOK) Qh[((size_t)h * N_TOK + m) * 64 + n] = f2bf(acc[mb][r]);
      }
  } else {
    ushort* dst = (which == 1) ? Kc : Vc;
#pragma unroll
    for (int mb = 0; mb < 4; ++mb)
#pragma unroll
      for (int r = 0; r < 4; ++r) {
        const int m = m0 + mb * 16 + quad * 4 + r;
        if (m < NK_TOK) {
          const int slot = inv[m];
          if (slot >= 0) dst[((size_t)h * NKPAD + slot) * 64 + n] = f2bf(acc[mb][r]);
        }
      }
  }
}

// output projection: fp32 out + bias
__global__ __launch_bounds__(256) void gemm_out_kernel(
    const ushort* __restrict__ Am, const ushort* __restrict__ Wpb,
    const float* __restrict__ bp, float* __restrict__ out) {
  __shared__ ushort As[64][72], Bs[64][72];
  const int t = threadIdx.x, w = t >> 6, lane = t & 63;
  const int quad = lane >> 4, l15 = lane & 15;
  const int m0 = blockIdx.x * 64;
  const int h = blockIdx.y;
  f32x4 acc[4];
#pragma unroll
  for (int i = 0; i < 4; ++i) acc[i] = (f32x4){0.f, 0.f, 0.f, 0.f};
  gemm_core(Am + (size_t)m0 * C_DIM, Wpb + (size_t)h * 64 * C_DIM,
            As, Bs, t, w, quad, l15, acc);
  const int n = w * 16 + l15;
  const float bb = bp[h * 64 + n];
#pragma unroll
  for (int mb = 0; mb < 4; ++mb)
#pragma unroll
    for (int r = 0; r < 4; ++r) {
      const int m = m0 + mb * 16 + quad * 4 + r;
      if (m < N_TOK) out[(size_t)m * C_DIM + h * 64 + n] = acc[mb][r] + bb;
    }
}

// ---------------------------------------------------------------------------
// Vc [h][slot][d] -> Vt [h][d][slot] (coalesced LDS transpose)
__global__ __launch_bounds__(256) void vtrans_kernel(const ushort* __restrict__ Vc,
                                                     ushort* __restrict__ Vt) {
  __shared__ ushort T[64][72];
  const int c = blockIdx.x, h = blockIdx.y, t = threadIdx.x;
#pragma unroll
  for (int i = 0; i < 2; ++i) {
    const int s = t + i * 256, r = s >> 3, g = s & 7;
    *(u8*)&T[r][g * 8] =
        *(const u8*)&Vc[((size_t)h * NKPAD + c * 64 + r) * 64 + g * 8];
  }
  __syncthreads();
#pragma unroll
  for (int i = 0; i < 2; ++i) {
    const int s = t + i * 256, d = s >> 3, g = s & 7;
    u8 o;
#pragma unroll
    for (int j = 0; j < 8; ++j) o[j] = T[g * 8 + j][d];
    *(u8*)&Vt[((size_t)h * 64 + d) * NKPAD + c * 64 + g * 8] = o;
  }
}

// ---------------------------------------------------------------------------
// MFMA flash attention (r2 hot structure): 16 q/wave, S^T = K.Q^T per wave,
// padded LDS, synchronous u8 staging with VGPR prefetch of the next chunk.
// grid (65 q-tiles of 64, 6 heads, 3 key slices). No fences, no cross-block.
__global__ __launch_bounds__(256) void attn_kernel(
    const ushort* __restrict__ Qh, const ushort* __restrict__ Kc,
    const ushort* __restrict__ Vt, const int* __restrict__ nkp,
    ushort* __restrict__ Opart, float* __restrict__ Lpart) {
  __shared__ ushort Ks[64][72];   // [slot][d]
  __shared__ ushort Vs[64][72];   // [d][slot]
  __shared__ ushort Ps[4][16][72];
  const int t = threadIdx.x, w = t >> 6, lane = t & 63;
  const int quad = lane >> 4, l15 = lane & 15;
  const int h = blockIdx.y, slice = blockIdx.z;
  const int q0 = blockIdx.x * 64;
  const int nk = *nkp, nchunk = (nk + 63) >> 6;
  const int g = t & 7;

  bh8 qf0, qf1;
  {
    int qr = q0 + w * 16 + l15;
    if (qr > N_TOK - 1) qr = N_TOK - 1;        // clamp (stores guarded)
    const ushort* qp = Qh + ((size_t)h * N_TOK + qr) * 64 + quad * 8;
    qf0 = *(const bh8*)qp;
    qf1 = *(const bh8*)(qp + 32);
  }
  f32x4 oacc[4];
#pragma unroll
  for (int i = 0; i < 4; ++i) oacc[i] = (f32x4){0.f, 0.f, 0.f, 0.f};
  float l_r = 0.f;

  const ushort* kb = Kc + (size_t)h * NKPAD * 64;
  const ushort* vb = Vt + (size_t)h * 64 * NKPAD;

  u8 rk[2], rv[2];
  if (slice < nchunk) {
#pragma unroll
    for (int it = 0; it < 2; ++it) {
      const int r = it * 32 + (t >> 3);
      rk[it] = *(const u8*)&kb[(size_t)(slice * 64 + r) * 64 + g * 8];
      rv[it] = *(const u8*)&vb[(size_t)r * NKPAD + slice * 64 + g * 8];
    }
  }
#pragma unroll 1
  for (int kc = slice; kc < nchunk; kc += 3) {
    __syncthreads();                          // previous chunk's readers done
#pragma unroll
    for (int it = 0; it < 2; ++it) {
      const int r = it * 32 + (t >> 3);
      *(u8*)&Ks[r][g * 8] = rk[it];
      *(u8*)&Vs[r][g * 8] = rv[it];
    }
    __syncthreads();
    if (kc + 3 < nchunk) {                    // prefetch next chunk into VGPRs
#pragma unroll
      for (int it = 0; it < 2; ++it) {
        const int r = it * 32 + (t >> 3);
        rk[it] = *(const u8*)&kb[(size_t)((kc + 3) * 64 + r) * 64 + g * 8];
        rv[it] = *(const u8*)&vb[(size_t)r * NKPAD + (kc + 3) * 64 + g * 8];
      }
    }
    float csum = 0.f;
#pragma unroll
    for (int f = 0; f < 4; ++f) {
      f32x4 s4 = {0.f, 0.f, 0.f, 0.f};
      const bh8 a0 = *(const bh8*)&Ks[f * 16 + l15][quad * 8];
      const bh8 a1 = *(const bh8*)&Ks[f * 16 + l15][32 + quad * 8];
      s4 = __builtin_amdgcn_mfma_f32_16x16x32_bf16(a0, qf0, s4, 0, 0, 0);
      s4 = __builtin_amdgcn_mfma_f32_16x16x32_bf16(a1, qf1, s4, 0, 0, 0);
      const int keyb = kc * 64 + f * 16 + quad * 4;
      u4 pv;
#pragma unroll
      for (int r = 0; r < 4; ++r) {
        const float p = (keyb + r < nk) ? __expf(s4[r]) : 0.f;
        csum += p;
        pv[r] = f2bf(p);
      }
      *(u4*)&Ps[w][l15][f * 16 + quad * 4] = pv;
    }
    csum += __shfl_xor(csum, 16);
    csum += __shfl_xor(csum, 32);
    l_r += csum;

    const bh8 pa0 = *(const bh8*)&Ps[w][l15][quad * 8];
    const bh8 pa1 = *(const bh8*)&Ps[w][l15][32 + quad * 8];
#pragma unroll
    for (int db = 0; db < 4; ++db) {
      const bh8 b0 = *(const bh8*)&Vs[db * 16 + l15][quad * 8];
      const bh8 b1 = *(const bh8*)&Vs[db * 16 + l15][32 + quad * 8];
      oacc[db] = __builtin_amdgcn_mfma_f32_16x16x32_bf16(pa0, b0, oacc[db], 0, 0, 0);
      oacc[db] = __builtin_amdgcn_mfma_f32_16x16x32_bf16(pa1, b1, oacc[db], 0, 0, 0);
    }
  }

  const int sh = slice * 6 + h;
  const int qg = q0 + w * 16;
#pragma unroll
  for (int db = 0; db < 4; ++db)
#pragma unroll
    for (int r = 0; r < 4; ++r) {
      const int q = qg + quad * 4 + r;
      if (q < N_TOK)
        Opart[((size_t)sh * NKPAD + q) * 64 + db * 16 + l15] = f2bf(oacc[db][r]);
    }
  if (quad == 0) {
    const int q = qg + l15;
    if (q < N_TOK) Lpart[sh * NKPAD + q] = l_r;
  }
}

// merge 3 key-slice partials -> bf16 Am [4160][384]
__global__ __launch_bounds__(256) void merge_kernel(const ushort* __restrict__ Opart,
                                                    const float* __restrict__ Lpart,
                                                    ushort* __restrict__ Am) {
  const int idx = blockIdx.x * 256 + threadIdx.x;     // u8 chunk index
  if (idx >= N_TOK * 48) return;
  const int q = idx / 48, c = (idx % 48) * 8;
  const int h = c >> 6, d = c & 63;
  float l = 0.f;
#pragma unroll
  for (int s = 0; s < 3; ++s) l += Lpart[(s * 6 + h) * NKPAD + q];
  const float inv = 1.f / l;
  float o[8] = {0.f, 0.f, 0.f, 0.f, 0.f, 0.f, 0.f, 0.f};
#pragma unroll
  for (int s = 0; s < 3; ++s) {
    const u8 v = *(const u8*)&Opart[((size_t)(s * 6 + h) * NKPAD + q) * 64 + d];
#pragma unroll
    for (int j = 0; j < 8; ++j) o[j] += bf2f(v[j]);
  }
  u8 r;
#pragma unroll
  for (int j = 0; j < 8; ++j) r[j] = f2bf(o[j] * inv);
  *(u8*)&Am[(size_t)q * C_DIM + c] = r;
}

// ---------------------------------------------------------------------------
extern "C" void kernel_launch(void* const* d_in, const int* in_sizes, int n_in,
                              void* d_out, int out_size, void* d_ws, size_t ws_size,
                              hipStream_t stream) {
  const float* x          = (const float*)d_in[0];
  const float* pos        = (const float*)d_in[1];
  const float* mask       = (const float*)d_in[2];
  const float* mask_block = (const float*)d_in[3];
  const float* Wq         = (const float*)d_in[4];
  const float* Wk         = (const float*)d_in[5];
  const float* Wv         = (const float*)d_in[6];
  const float* Wp         = (const float*)d_in[7];
  const float* bp         = (const float*)d_in[8];
  float* out = (float*)d_out;
  char* wsb = (char*)d_ws;

  float*  pooled_part = (float*)wsb;                // [128][384]
  float*  cnt_part    = (float*)(wsb + 196608);     // [128]
  int*    nk          = (int*)(wsb + 197120);
  int*    inv         = (int*)(wsb + 197632);       // [4099]
  ushort* Aq          = (ushort*)(wsb + 215296);    // [4160][384]
  ushort* Ak          = (ushort*)(wsb + 3410176);   // [4160][384]
  ushort* Av          = (ushort*)(wsb + 6605056);   // [4160][384]
  ushort* Wb          = (ushort*)(wsb + 9799936);   // [4][384][384]
  ushort* Qh          = (ushort*)(wsb + 10979584);  // [6][4098][64]
  ushort* Kc          = (ushort*)(wsb + 14126848);  // [6][4160][64]
  ushort* Vc          = (ushort*)(wsb + 17321728);  // [6][4160][64]
  ushort* Vt          = (ushort*)(wsb + 20516608);  // [6][64][4160]
  float*  Lp          = (float*)(wsb + 23711488);   // [18][4160]
  ushort* Am          = (ushort*)(wsb + 24011008);  // [4160][384]
  ushort* Op          = Aq;  // [18][4160][64] overlays Aq/Ak/Av (dead after gemm3)

  pool_kernel<<<dim3(128), dim3(384), 0, stream>>>(x, mask, pooled_part, cnt_part);
  prep_kernel<<<dim3(293), dim3(256), 0, stream>>>(x, pos, pooled_part, cnt_part,
                                                   Wq, Wk, Wv, Wp, mask, mask_block,
                                                   Aq, Ak, Av, Wb, nk, inv);
  gemm3_kernel<<<dim3(65, 18), 256, 0, stream>>>(Aq, Ak, Av, Wb, inv, Qh, Kc, Vc);
  vtrans_kernel<<<dim3(65, 6), 256, 0, stream>>>(Vc, Vt);
  attn_kernel<<<dim3(65, 6, 3), 256, 0, stream>>>(Qh, Kc, Vt, nk, Op, Lp);
  merge_kernel<<<dim3(769), 256, 0, stream>>>(Op, Lp, Am);
  gemm_out_kernel<<<dim3(65, 6), 256, 0, stream>>>(Am, Wb + 3 * 147456, bp, out);
}